// Round 1
// baseline (2029.198 us; speedup 1.0000x reference)
//
#include <hip/hip_runtime.h>
#include <cstddef>

#define NB 16
#define LIN 512
#define DM 384
#define DC 1536
#define MELMAX 4096
#define LN_EPS 1e-5f

// ---------------------------------------------------------------- utilities

__device__ __forceinline__ float wred(float v) {
#pragma unroll
    for (int m = 32; m >= 1; m >>= 1) v += __shfl_xor(v, m, 64);
    return v;
}

// ---------------------------------------------------------------- cumsum (per batch, Hillis-Steele)

__global__ void cumsum_kernel(const int* __restrict__ tgt, int* __restrict__ cum) {
    __shared__ int s[LIN];
    const int b = blockIdx.x, tid = threadIdx.x;
    s[tid] = tgt[b * LIN + tid];
    __syncthreads();
    for (int off = 1; off < LIN; off <<= 1) {
        int v = (tid >= off) ? s[tid - off] : 0;
        __syncthreads();
        s[tid] += v;
        __syncthreads();
    }
    cum[b * LIN + tid] = s[tid];
}

// ---------------------------------------------------------------- length-regulate gather
// one wave per output frame; binary search (searchsorted side='right') + float4 row copy

__global__ __launch_bounds__(256) void gather_kernel(const float* __restrict__ x,
                                                     const int* __restrict__ cum,
                                                     float* __restrict__ out) {
    const int wid = (blockIdx.x * 256 + threadIdx.x) >> 6;  // global wave id = frame row
    const int lane = threadIdx.x & 63;
    const int b = wid >> 12;            // / 4096
    const int t = wid & (MELMAX - 1);
    const int* c = cum + b * LIN;
    const int total = c[LIN - 1];
    float4* orow = reinterpret_cast<float4*>(out + ((size_t)b * MELMAX + t) * DM);
    if (t < total) {
        // first idx with c[idx] > t
        int lo = 0, hi = LIN;
        while (lo < hi) { int mid = (lo + hi) >> 1; if (c[mid] > t) hi = mid; else lo = mid + 1; }
        const int idx = lo < (LIN - 1) ? lo : (LIN - 1);
        const float4* xrow = reinterpret_cast<const float4*>(x + ((size_t)b * LIN + idx) * DM);
#pragma unroll
        for (int j = 0; j < 2; ++j) {
            const int p = lane + 64 * j;
            if (p < DM / 4) orow[p] = xrow[p];
        }
    } else {
        const float4 z = make_float4(0.f, 0.f, 0.f, 0.f);
#pragma unroll
        for (int j = 0; j < 2; ++j) {
            const int p = lane + 64 * j;
            if (p < DM / 4) orow[p] = z;
        }
    }
}

// ---------------------------------------------------------------- conv1d(k=3, SAME) as tiled fp32 GEMM
// in:  (B, LIN, CI)  row-major ("position-major")
// w:   (CO, CI, 3)   original OIH layout, read directly (stride-3 scalar loads, L2-resident)
// out: (B, LIN, CO)  with bias + ReLU epilogue

template <int CI, int CO>
__global__ __launch_bounds__(256) void conv_gemm_kernel(const float* __restrict__ in,
                                                        const float* __restrict__ w,
                                                        const float* __restrict__ bias,
                                                        float* __restrict__ out) {
    constexpr int TM = 64, TN = 64, TK = 16, PAD = 16;  // PAD keeps 16B-aligned LDS rows for b128 reads
    __shared__ float As[TK][TM + PAD];  // K-major: As[k][l]
    __shared__ float Bs[TK][TN + PAD];  // K-major: Bs[k][co]

    const int b = blockIdx.z;
    const int l0 = blockIdx.y * TM;
    const int n0 = blockIdx.x * TN;
    const int tid = threadIdx.x;
    const int tx = tid & 15, ty = tid >> 4;        // 16x16 thread grid -> 4x4 micro-tile each
    const int lr = tid >> 2, lc = (tid & 3) * 4;   // loader: row 0..63, col-group 0..3

    const float* inb = in + (size_t)b * LIN * CI;
    float acc[4][4] = {};

    for (int t = 0; t < 3; ++t) {
        const int li = l0 + t - 1 + lr;            // SAME padding: shift by t-1
        const bool ok = (li >= 0) && (li < LIN);
        for (int k0 = 0; k0 < CI; k0 += TK) {
            float4 av = make_float4(0.f, 0.f, 0.f, 0.f);
            if (ok) av = *reinterpret_cast<const float4*>(inb + (size_t)li * CI + k0 + lc);
            // weight: w[n0+lr][k0+lc+q][t], stride-3 scalars (L2-cached, once per 256-FMA chunk)
            const float* wrow = w + ((size_t)(n0 + lr) * CI + (k0 + lc)) * 3 + t;
            const float w0 = wrow[0], w1_ = wrow[3], w2_ = wrow[6], w3_ = wrow[9];
            As[lc + 0][lr] = av.x; As[lc + 1][lr] = av.y; As[lc + 2][lr] = av.z; As[lc + 3][lr] = av.w;
            Bs[lc + 0][lr] = w0;   Bs[lc + 1][lr] = w1_;  Bs[lc + 2][lr] = w2_;  Bs[lc + 3][lr] = w3_;
            __syncthreads();
#pragma unroll
            for (int kk = 0; kk < TK; ++kk) {
                float a[4], bb[4];
#pragma unroll
                for (int i = 0; i < 4; ++i) a[i] = As[kk][ty * 4 + i];
#pragma unroll
                for (int j = 0; j < 4; ++j) bb[j] = Bs[kk][tx * 4 + j];
#pragma unroll
                for (int i = 0; i < 4; ++i)
#pragma unroll
                    for (int j = 0; j < 4; ++j)
                        acc[i][j] = fmaf(a[i], bb[j], acc[i][j]);
            }
            __syncthreads();
        }
    }

    const float4 bv = *reinterpret_cast<const float4*>(bias + n0 + tx * 4);
    float* outb = out + (size_t)b * LIN * CO;
#pragma unroll
    for (int i = 0; i < 4; ++i) {
        const int l = l0 + ty * 4 + i;
        float4 r;
        r.x = fmaxf(acc[i][0] + bv.x, 0.f);
        r.y = fmaxf(acc[i][1] + bv.y, 0.f);
        r.z = fmaxf(acc[i][2] + bv.z, 0.f);
        r.w = fmaxf(acc[i][3] + bv.w, 0.f);
        *reinterpret_cast<float4*>(outb + (size_t)l * CO + n0 + tx * 4) = r;
    }
}

// ---------------------------------------------------------------- LayerNorm (one wave per row, in-place)

__global__ void ln_kernel(float* __restrict__ h, const float* __restrict__ g,
                          const float* __restrict__ be) {
    const int row = blockIdx.x, lane = threadIdx.x;
    float* hr = h + (size_t)row * DM;
    float v[6];
    float s = 0.f;
#pragma unroll
    for (int j = 0; j < 6; ++j) { v[j] = hr[lane + 64 * j]; s += v[j]; }
    s = wred(s);
    const float mean = s * (1.f / DM);
    float vs = 0.f;
#pragma unroll
    for (int j = 0; j < 6; ++j) { const float d = v[j] - mean; vs += d * d; }
    vs = wred(vs);
    const float rstd = rsqrtf(vs * (1.f / DM) + LN_EPS);
#pragma unroll
    for (int j = 0; j < 6; ++j) {
        const int c = lane + 64 * j;
        hr[c] = (v[j] - mean) * rstd * g[c] + be[c];
    }
}

// ---------------------------------------------------------------- LayerNorm + linear(384->1) fused

__global__ void ln_linear_kernel(const float* __restrict__ h, const float* __restrict__ g,
                                 const float* __restrict__ be, const float* __restrict__ wl,
                                 const float* __restrict__ bl, float* __restrict__ dur) {
    const int row = blockIdx.x, lane = threadIdx.x;
    const float* hr = h + (size_t)row * DM;
    float v[6];
    float s = 0.f;
#pragma unroll
    for (int j = 0; j < 6; ++j) { v[j] = hr[lane + 64 * j]; s += v[j]; }
    s = wred(s);
    const float mean = s * (1.f / DM);
    float vs = 0.f;
#pragma unroll
    for (int j = 0; j < 6; ++j) { const float d = v[j] - mean; vs += d * d; }
    vs = wred(vs);
    const float rstd = rsqrtf(vs * (1.f / DM) + LN_EPS);
    float dot = 0.f;
#pragma unroll
    for (int j = 0; j < 6; ++j) {
        const int c = lane + 64 * j;
        dot += ((v[j] - mean) * rstd * g[c] + be[c]) * wl[c];
    }
    dot = wred(dot);
    if (lane == 0) dur[row] = dot + bl[0];
}

// ---------------------------------------------------------------- launch

extern "C" void kernel_launch(void* const* d_in, const int* in_sizes, int n_in,
                              void* d_out, int out_size, void* d_ws, size_t ws_size,
                              hipStream_t stream) {
    const float* x   = (const float*)d_in[0];
    const int*   tgt = (const int*)d_in[1];
    // d_in[2] = mel_max_len (4096, compile-time constant here)
    const float* w1  = (const float*)d_in[3];
    const float* b1  = (const float*)d_in[4];
    const float* w2  = (const float*)d_in[5];
    const float* b2  = (const float*)d_in[6];
    const float* g1  = (const float*)d_in[7];
    const float* be1 = (const float*)d_in[8];
    const float* w3  = (const float*)d_in[9];
    const float* b3  = (const float*)d_in[10];
    const float* w4  = (const float*)d_in[11];
    const float* b4  = (const float*)d_in[12];
    const float* g2  = (const float*)d_in[13];
    const float* be2 = (const float*)d_in[14];
    const float* wl  = (const float*)d_in[15];
    const float* bl  = (const float*)d_in[16];

    float* out = (float*)d_out;                        // (16, 4096, 384)
    float* dur = out + (size_t)NB * MELMAX * DM;       // (16, 512)

    // workspace layout (~63 MB)
    float* ws = (float*)d_ws;
    float* hbig = ws;                                   // (16, 512, 1536)
    float* hsml = hbig + (size_t)NB * LIN * DC;         // (16, 512, 384)
    int*   cum  = (int*)(hsml + (size_t)NB * LIN * DM); // (16, 512)

    // ---- output 0: length regulate
    cumsum_kernel<<<NB, LIN, 0, stream>>>(tgt, cum);
    gather_kernel<<<(NB * MELMAX) / 4, 256, 0, stream>>>(x, cum, out);

    // ---- output 1: duration predictor
    conv_gemm_kernel<DM, DC><<<dim3(DC / 64, LIN / 64, NB), 256, 0, stream>>>(x, w1, b1, hbig);
    conv_gemm_kernel<DC, DM><<<dim3(DM / 64, LIN / 64, NB), 256, 0, stream>>>(hbig, w2, b2, hsml);
    ln_kernel<<<NB * LIN, 64, 0, stream>>>(hsml, g1, be1);
    conv_gemm_kernel<DM, DC><<<dim3(DC / 64, LIN / 64, NB), 256, 0, stream>>>(hsml, w3, b3, hbig);
    conv_gemm_kernel<DC, DM><<<dim3(DM / 64, LIN / 64, NB), 256, 0, stream>>>(hbig, w4, b4, hsml);
    ln_linear_kernel<<<NB * LIN, 64, 0, stream>>>(hsml, g2, be2, wl, bl, dur);
}

// Round 2
// 318.601 us; speedup vs baseline: 6.3691x; 6.3691x over previous
//
#include <hip/hip_runtime.h>
#include <hip/hip_bf16.h>
#include <cstddef>
#include <cstdint>

#define NB 16
#define LIN 512
#define DM 384
#define DC 1536
#define MELMAX 4096
#define LN_EPS 1e-5f

typedef __bf16 bf16x8 __attribute__((ext_vector_type(8)));
typedef float f32x4 __attribute__((ext_vector_type(4)));

#define GL2LDS(gp, lp)                                                                \
    __builtin_amdgcn_global_load_lds((const __attribute__((address_space(1))) void*)(gp), \
                                     (__attribute__((address_space(3))) void*)(lp), 16, 0, 0)

__device__ __forceinline__ float wred(float v) {
#pragma unroll
    for (int m = 32; m >= 1; m >>= 1) v += __shfl_xor(v, m, 64);
    return v;
}

__device__ __forceinline__ unsigned short f2bf(float f) {
    __hip_bfloat16 h = __float2bfloat16(f);
    return *reinterpret_cast<unsigned short*>(&h);
}

__device__ __forceinline__ float bf2f(unsigned short u) {
    return __uint_as_float(((unsigned)u) << 16);
}

// ---------------------------------------------------------------- cumsum (per batch, Hillis-Steele)

__global__ void cumsum_kernel(const int* __restrict__ tgt, int* __restrict__ cum) {
    __shared__ int s[LIN];
    const int b = blockIdx.x, tid = threadIdx.x;
    s[tid] = tgt[b * LIN + tid];
    __syncthreads();
    for (int off = 1; off < LIN; off <<= 1) {
        int v = (tid >= off) ? s[tid - off] : 0;
        __syncthreads();
        s[tid] += v;
        __syncthreads();
    }
    cum[b * LIN + tid] = s[tid];
}

// ---------------------------------------------------------------- length-regulate gather

__global__ __launch_bounds__(256) void gather_kernel(const float* __restrict__ x,
                                                     const int* __restrict__ cum,
                                                     float* __restrict__ out) {
    const int wid = (blockIdx.x * 256 + threadIdx.x) >> 6;
    const int lane = threadIdx.x & 63;
    const int b = wid >> 12;
    const int t = wid & (MELMAX - 1);
    const int* c = cum + b * LIN;
    const int total = c[LIN - 1];
    float4* orow = reinterpret_cast<float4*>(out + ((size_t)b * MELMAX + t) * DM);
    if (t < total) {
        int lo = 0, hi = LIN;
        while (lo < hi) { int mid = (lo + hi) >> 1; if (c[mid] > t) hi = mid; else lo = mid + 1; }
        const int idx = lo < (LIN - 1) ? lo : (LIN - 1);
        const float4* xrow = reinterpret_cast<const float4*>(x + ((size_t)b * LIN + idx) * DM);
#pragma unroll
        for (int j = 0; j < 2; ++j) {
            const int p = lane + 64 * j;
            if (p < DM / 4) orow[p] = xrow[p];
        }
    } else {
        const float4 z = make_float4(0.f, 0.f, 0.f, 0.f);
#pragma unroll
        for (int j = 0; j < 2; ++j) {
            const int p = lane + 64 * j;
            if (p < DM / 4) orow[p] = z;
        }
    }
}

// ---------------------------------------------------------------- small prep kernels

// zero the pad rows (row 0 and row LIN+1 of each batch) of a padded bf16 buffer
__global__ void zpad_kernel(unsigned short* __restrict__ p, int rowlen) {
    const int b = blockIdx.x >> 1;
    const int row = (blockIdx.x & 1) ? (LIN + 1) : 0;
    unsigned short* base = p + ((size_t)b * (LIN + 2) + row) * rowlen;
    for (int c = threadIdx.x; c < rowlen; c += 256) base[c] = 0;
}

// cast x (B, LIN, DM) f32 -> padded bf16 (B, LIN+2, DM) at row+1
__global__ void cast_x_kernel(const float* __restrict__ x, unsigned short* __restrict__ xb) {
    const int idx = blockIdx.x * 256 + threadIdx.x;   // one per 4 elems
    const int total = NB * LIN * DM / 4;
    if (idx >= total) return;
    const float4 v = reinterpret_cast<const float4*>(x)[idx];
    const int e = idx * 4;
    const int b = e / (LIN * DM);
    const int rem = e - b * (LIN * DM);
    const int l = rem / DM;
    const int c = rem - l * DM;
    ushort4 o;
    o.x = f2bf(v.x); o.y = f2bf(v.y); o.z = f2bf(v.z); o.w = f2bf(v.w);
    *reinterpret_cast<ushort4*>(xb + ((size_t)b * (LIN + 2) + l + 1) * DM + c) = o;
}

// cast w (CO, CI, 3) f32 -> wg (CO, 3*CI) bf16 with k = t*CI + ci
template <int CI, int CO>
__global__ void wcast_kernel(const float* __restrict__ w, unsigned short* __restrict__ wg) {
    const int idx = blockIdx.x * 256 + threadIdx.x;   // one per (co, ci)
    if (idx >= CO * CI) return;
    const int co = idx / CI;
    const int ci = idx - co * CI;
    const float* p = w + (size_t)idx * 3;
    unsigned short* o = wg + (size_t)co * (3 * CI) + ci;
    o[0 * CI] = f2bf(p[0]);
    o[1 * CI] = f2bf(p[1]);
    o[2 * CI] = f2bf(p[2]);
}

// ---------------------------------------------------------------- conv1d(k=3,SAME) as bf16 MFMA GEMM
// in:  (NB, LIN+2, CI) bf16, zero-padded rows (position p stored at row p+1)
// wg:  (CO, 3*CI) bf16, k = t*CI + ci
// out: (NB, LIN+2, CO) bf16, written at row+1, bias+ReLU epilogue

template <int CI, int CO>
__global__ __launch_bounds__(256, 2) void conv_mfma_kernel(const unsigned short* __restrict__ in,
                                                           const unsigned short* __restrict__ wg,
                                                           const float* __restrict__ bias,
                                                           unsigned short* __restrict__ out) {
    constexpr int BM = 128, BN = 128, BK = 32;
    constexpr int KC = CI / BK;                    // K-steps per tap
    __shared__ __align__(16) unsigned short As[BM * BK];  // row-major [128][32]
    __shared__ __align__(16) unsigned short Bs[BN * BK];  // n-major  [128][32]

    const int b = blockIdx.z;
    const int l0 = blockIdx.y * BM;
    const int n0 = blockIdx.x * BN;
    const int tid = threadIdx.x;
    const int lane = tid & 63;
    const int wv = tid >> 6;
    const int wr = wv >> 1, wc = wv & 1;           // 2x2 wave grid, each wave 64x64 out

    const unsigned short* inb = in + (size_t)b * (LIN + 2) * CI;

    f32x4 acc[4][4];
#pragma unroll
    for (int m = 0; m < 4; ++m)
#pragma unroll
        for (int n = 0; n < 4; ++n) acc[m][n] = (f32x4){0.f, 0.f, 0.f, 0.f};

    const int lrow = lane >> 2;   // staging: lane -> row-within-16
    const int lch = lane & 3;     // staging: lane -> 16B chunk

    for (int t = 0; t < 3; ++t) {
        // position = l0 + r + lrow + (t-1); padded row index = that + 1 = l0 + r + lrow + t
        const unsigned short* at = inb + (size_t)(l0 + t) * CI;
        const unsigned short* bt = wg + (size_t)t * CI;
        for (int kb = 0; kb < KC; ++kb) {
            const int kin = kb * BK;
            {
                const int rbase = wv * 32;
#pragma unroll
                for (int i = 0; i < 2; ++i) {
                    const int r = rbase + i * 16;
                    const unsigned short* ga = at + (size_t)(r + lrow) * CI + kin + lch * 8;
                    GL2LDS(ga, As + r * BK);
                    const unsigned short* gb =
                        bt + (size_t)(n0 + r + lrow) * (3 * CI) + kin + lch * 8;
                    GL2LDS(gb, Bs + r * BK);
                }
            }
            __syncthreads();
            {
                const int fr = lane & 15, kg = lane >> 4;
                bf16x8 aF[4], bF[4];
#pragma unroll
                for (int m = 0; m < 4; ++m)
                    aF[m] = *reinterpret_cast<const bf16x8*>(As + (wr * 64 + m * 16 + fr) * BK + kg * 8);
#pragma unroll
                for (int n = 0; n < 4; ++n)
                    bF[n] = *reinterpret_cast<const bf16x8*>(Bs + (wc * 64 + n * 16 + fr) * BK + kg * 8);
#pragma unroll
                for (int m = 0; m < 4; ++m)
#pragma unroll
                    for (int n = 0; n < 4; ++n)
                        acc[m][n] = __builtin_amdgcn_mfma_f32_16x16x32_bf16(aF[m], bF[n], acc[m][n], 0, 0, 0);
            }
            __syncthreads();
        }
    }

    // epilogue: bias + ReLU -> bf16, C/D layout col=lane&15, row=(lane>>4)*4+reg
    const int fr = lane & 15, fq = lane >> 4;
    float bv[4];
#pragma unroll
    for (int n = 0; n < 4; ++n) bv[n] = bias[n0 + wc * 64 + n * 16 + fr];
    unsigned short* outb = out + (size_t)b * (LIN + 2) * CO;
#pragma unroll
    for (int m = 0; m < 4; ++m)
#pragma unroll
        for (int q = 0; q < 4; ++q) {
            const int grow = l0 + wr * 64 + m * 16 + fq * 4 + q + 1;  // +1 pad
            unsigned short* orow = outb + (size_t)grow * CO + n0 + wc * 64 + fr;
#pragma unroll
            for (int n = 0; n < 4; ++n) {
                const float v = fmaxf(acc[m][n][q] + bv[n], 0.f);
                orow[n * 16] = f2bf(v);
            }
        }
}

// ---------------------------------------------------------------- LayerNorm over bf16 padded buffer (in place)

__global__ void ln_kernel(unsigned short* __restrict__ h, const float* __restrict__ g,
                          const float* __restrict__ be) {
    const int row = blockIdx.x, lane = threadIdx.x;
    const int b = row >> 9, l = row & (LIN - 1);
    unsigned short* hr = h + ((size_t)b * (LIN + 2) + l + 1) * DM;
    float v[6];
    float s = 0.f;
#pragma unroll
    for (int j = 0; j < 6; ++j) { v[j] = bf2f(hr[lane + 64 * j]); s += v[j]; }
    s = wred(s);
    const float mean = s * (1.f / DM);
    float vs = 0.f;
#pragma unroll
    for (int j = 0; j < 6; ++j) { const float d = v[j] - mean; vs += d * d; }
    vs = wred(vs);
    const float rstd = rsqrtf(vs * (1.f / DM) + LN_EPS);
#pragma unroll
    for (int j = 0; j < 6; ++j) {
        const int c = lane + 64 * j;
        hr[c] = f2bf((v[j] - mean) * rstd * g[c] + be[c]);
    }
}

// ---------------------------------------------------------------- LayerNorm + linear(384->1), bf16 in, f32 out

__global__ void ln_linear_kernel(const unsigned short* __restrict__ h, const float* __restrict__ g,
                                 const float* __restrict__ be, const float* __restrict__ wl,
                                 const float* __restrict__ bl, float* __restrict__ dur) {
    const int row = blockIdx.x, lane = threadIdx.x;
    const int b = row >> 9, l = row & (LIN - 1);
    const unsigned short* hr = h + ((size_t)b * (LIN + 2) + l + 1) * DM;
    float v[6];
    float s = 0.f;
#pragma unroll
    for (int j = 0; j < 6; ++j) { v[j] = bf2f(hr[lane + 64 * j]); s += v[j]; }
    s = wred(s);
    const float mean = s * (1.f / DM);
    float vs = 0.f;
#pragma unroll
    for (int j = 0; j < 6; ++j) { const float d = v[j] - mean; vs += d * d; }
    vs = wred(vs);
    const float rstd = rsqrtf(vs * (1.f / DM) + LN_EPS);
    float dot = 0.f;
#pragma unroll
    for (int j = 0; j < 6; ++j) {
        const int c = lane + 64 * j;
        dot += ((v[j] - mean) * rstd * g[c] + be[c]) * wl[c];
    }
    dot = wred(dot);
    if (lane == 0) dur[row] = dot + bl[0];
}

// ---------------------------------------------------------------- launch

extern "C" void kernel_launch(void* const* d_in, const int* in_sizes, int n_in,
                              void* d_out, int out_size, void* d_ws, size_t ws_size,
                              hipStream_t stream) {
    const float* x   = (const float*)d_in[0];
    const int*   tgt = (const int*)d_in[1];
    const float* w1  = (const float*)d_in[3];
    const float* b1  = (const float*)d_in[4];
    const float* w2  = (const float*)d_in[5];
    const float* b2  = (const float*)d_in[6];
    const float* g1  = (const float*)d_in[7];
    const float* be1 = (const float*)d_in[8];
    const float* w3  = (const float*)d_in[9];
    const float* b3  = (const float*)d_in[10];
    const float* w4  = (const float*)d_in[11];
    const float* b4  = (const float*)d_in[12];
    const float* g2  = (const float*)d_in[13];
    const float* be2 = (const float*)d_in[14];
    const float* wl  = (const float*)d_in[15];
    const float* bl  = (const float*)d_in[16];

    float* out = (float*)d_out;                         // (16, 4096, 384) f32
    float* dur = out + (size_t)NB * MELMAX * DM;        // (16, 512) f32

    // workspace layout (bf16 buffers as ushort), ~52 MB
    unsigned short* ws = (unsigned short*)d_ws;
    unsigned short* xb   = ws;                               // (16, 514, 384)  also conv4 out
    unsigned short* hbig = xb + (size_t)NB * (LIN + 2) * DM; // (16, 514, 1536) conv1/conv3 out
    unsigned short* h2b  = hbig + (size_t)NB * (LIN + 2) * DC; // (16, 514, 384) conv2 out
    unsigned short* wg1  = h2b + (size_t)NB * (LIN + 2) * DM;  // (1536, 1152)
    unsigned short* wg2  = wg1 + (size_t)DC * 3 * DM;          // (384, 4608)
    unsigned short* wg3  = wg2 + (size_t)DM * 3 * DC;          // (1536, 1152)
    unsigned short* wg4  = wg3 + (size_t)DC * 3 * DM;          // (384, 4608)
    int* cum = (int*)(wg4 + (size_t)DM * 3 * DC);              // (16, 512)

    // ---- output 0: length regulate
    cumsum_kernel<<<NB, LIN, 0, stream>>>(tgt, cum);
    gather_kernel<<<(NB * MELMAX) / 4, 256, 0, stream>>>(x, cum, out);

    // ---- prep: pads, casts
    zpad_kernel<<<NB * 2, 256, 0, stream>>>(xb, DM);
    zpad_kernel<<<NB * 2, 256, 0, stream>>>(hbig, DC);
    zpad_kernel<<<NB * 2, 256, 0, stream>>>(h2b, DM);
    cast_x_kernel<<<(NB * LIN * DM / 4 + 255) / 256, 256, 0, stream>>>(x, xb);
    wcast_kernel<DM, DC><<<(DC * DM + 255) / 256, 256, 0, stream>>>(w1, wg1);
    wcast_kernel<DC, DM><<<(DM * DC + 255) / 256, 256, 0, stream>>>(w2, wg2);
    wcast_kernel<DM, DC><<<(DC * DM + 255) / 256, 256, 0, stream>>>(w3, wg3);
    wcast_kernel<DC, DM><<<(DM * DC + 255) / 256, 256, 0, stream>>>(w4, wg4);

    // ---- output 1: duration predictor (bf16 MFMA convs)
    conv_mfma_kernel<DM, DC><<<dim3(DC / 128, LIN / 128, NB), 256, 0, stream>>>(xb, wg1, b1, hbig);
    conv_mfma_kernel<DC, DM><<<dim3(DM / 128, LIN / 128, NB), 256, 0, stream>>>(hbig, wg2, b2, h2b);
    ln_kernel<<<NB * LIN, 64, 0, stream>>>(h2b, g1, be1);
    conv_mfma_kernel<DM, DC><<<dim3(DC / 128, LIN / 128, NB), 256, 0, stream>>>(h2b, wg3, b3, hbig);
    conv_mfma_kernel<DC, DM><<<dim3(DM / 128, LIN / 128, NB), 256, 0, stream>>>(hbig, wg4, b4, xb);
    ln_linear_kernel<<<NB * LIN, 64, 0, stream>>>(xb, g2, be2, wl, bl, dur);
}

// Round 3
// 242.561 us; speedup vs baseline: 8.3657x; 1.3135x over previous
//
#include <hip/hip_runtime.h>
#include <hip/hip_bf16.h>
#include <cstddef>
#include <cstdint>

#define NB 16
#define LIN 512
#define DM 384
#define DC 1536
#define MELMAX 4096
#define LN_EPS 1e-5f

typedef __bf16 bf16x8 __attribute__((ext_vector_type(8)));
typedef float f32x4 __attribute__((ext_vector_type(4)));

#define GL2LDS(gp, lp)                                                                \
    __builtin_amdgcn_global_load_lds((const __attribute__((address_space(1))) void*)(gp), \
                                     (__attribute__((address_space(3))) void*)(lp), 16, 0, 0)

__device__ __forceinline__ float wred(float v) {
#pragma unroll
    for (int m = 32; m >= 1; m >>= 1) v += __shfl_xor(v, m, 64);
    return v;
}

__device__ __forceinline__ unsigned short f2bf(float f) {
    __hip_bfloat16 h = __float2bfloat16(f);
    return *reinterpret_cast<unsigned short*>(&h);
}

__device__ __forceinline__ float bf2f(unsigned short u) {
    return __uint_as_float(((unsigned)u) << 16);
}

// ---------------------------------------------------------------- cumsum (per batch, Hillis-Steele)

__global__ void cumsum_kernel(const int* __restrict__ tgt, int* __restrict__ cum) {
    __shared__ int s[LIN];
    const int b = blockIdx.x, tid = threadIdx.x;
    s[tid] = tgt[b * LIN + tid];
    __syncthreads();
    for (int off = 1; off < LIN; off <<= 1) {
        int v = (tid >= off) ? s[tid - off] : 0;
        __syncthreads();
        s[tid] += v;
        __syncthreads();
    }
    cum[b * LIN + tid] = s[tid];
}

// ---------------------------------------------------------------- length-regulate gather

__global__ __launch_bounds__(256) void gather_kernel(const float* __restrict__ x,
                                                     const int* __restrict__ cum,
                                                     float* __restrict__ out) {
    const int wid = (blockIdx.x * 256 + threadIdx.x) >> 6;
    const int lane = threadIdx.x & 63;
    const int b = wid >> 12;
    const int t = wid & (MELMAX - 1);
    const int* c = cum + b * LIN;
    const int total = c[LIN - 1];
    float4* orow = reinterpret_cast<float4*>(out + ((size_t)b * MELMAX + t) * DM);
    if (t < total) {
        int lo = 0, hi = LIN;
        while (lo < hi) { int mid = (lo + hi) >> 1; if (c[mid] > t) hi = mid; else lo = mid + 1; }
        const int idx = lo < (LIN - 1) ? lo : (LIN - 1);
        const float4* xrow = reinterpret_cast<const float4*>(x + ((size_t)b * LIN + idx) * DM);
#pragma unroll
        for (int j = 0; j < 2; ++j) {
            const int p = lane + 64 * j;
            if (p < DM / 4) orow[p] = xrow[p];
        }
    } else {
        const float4 z = make_float4(0.f, 0.f, 0.f, 0.f);
#pragma unroll
        for (int j = 0; j < 2; ++j) {
            const int p = lane + 64 * j;
            if (p < DM / 4) orow[p] = z;
        }
    }
}

// ---------------------------------------------------------------- small prep kernels

__global__ void zpad_kernel(unsigned short* __restrict__ p, int rowlen) {
    const int b = blockIdx.x >> 1;
    const int row = (blockIdx.x & 1) ? (LIN + 1) : 0;
    unsigned short* base = p + ((size_t)b * (LIN + 2) + row) * rowlen;
    for (int c = threadIdx.x; c < rowlen; c += 256) base[c] = 0;
}

__global__ void cast_x_kernel(const float* __restrict__ x, unsigned short* __restrict__ xb) {
    const int idx = blockIdx.x * 256 + threadIdx.x;
    const int total = NB * LIN * DM / 4;
    if (idx >= total) return;
    const float4 v = reinterpret_cast<const float4*>(x)[idx];
    const int e = idx * 4;
    const int b = e / (LIN * DM);
    const int rem = e - b * (LIN * DM);
    const int l = rem / DM;
    const int c = rem - l * DM;
    ushort4 o;
    o.x = f2bf(v.x); o.y = f2bf(v.y); o.z = f2bf(v.z); o.w = f2bf(v.w);
    *reinterpret_cast<ushort4*>(xb + ((size_t)b * (LIN + 2) + l + 1) * DM + c) = o;
}

// w (CO, CI, 3) f32 -> wg (CO, 3*CI) bf16 with k = t*CI + ci
template <int CI, int CO>
__global__ void wcast_kernel(const float* __restrict__ w, unsigned short* __restrict__ wg) {
    const int idx = blockIdx.x * 256 + threadIdx.x;
    if (idx >= CO * CI) return;
    const int co = idx / CI;
    const int ci = idx - co * CI;
    const float* p = w + (size_t)idx * 3;
    unsigned short* o = wg + (size_t)co * (3 * CI) + ci;
    o[0 * CI] = f2bf(p[0]);
    o[1 * CI] = f2bf(p[1]);
    o[2 * CI] = f2bf(p[2]);
}

// ---------------------------------------------------------------- conv1d(k=3,SAME) as bf16 MFMA GEMM
// Tap-merged: per 32-wide K-block, stage A rows [l0 .. l0+143] once + 3 tap-shifted
// B tiles; 3 taps consume the same LDS A with row offsets. XCD-chunked swizzle,
// n-fastest within chunk.

template <int CI, int CO, int BN>
__global__ __launch_bounds__(256, 2) void conv_mfma_kernel(const unsigned short* __restrict__ in,
                                                           const unsigned short* __restrict__ wg,
                                                           const float* __restrict__ bias,
                                                           unsigned short* __restrict__ out) {
    constexpr int BM = 128, BK = 32;
    constexpr int KC = CI / BK;             // K-blocks
    constexpr int AROWS = BM + 16;          // 144 staged rows (need BM+2)
    constexpr int AGRP = AROWS / 16;        // 9
    constexpr int BGRP = 3 * BN / 16;       // 24 (BN=128) / 12 (BN=64)
    constexpr int GPT = BN / 16;            // row-groups per B tile
    constexpr int NW_N = BN / 32;           // n-frags per wave (wave covers BN/2 cols)
    constexpr int NT = CO / BN;
    constexpr int MT = LIN / BM;            // 4

    __shared__ __align__(16) unsigned short As[AROWS * BK];
    __shared__ __align__(16) unsigned short Bs[3 * BN * BK];

    // bijective XCD-chunk swizzle (m204): contiguous logical ranges per XCD
    const int orig = blockIdx.x, nwg = gridDim.x;
    const int q = nwg >> 3, r = nwg & 7, xcd = orig & 7, o = orig >> 3;
    const int wgid = (xcd < r ? xcd * (q + 1) : r * (q + 1) + (xcd - r) * q) + o;

    const int mg = wgid / NT;               // global m-tile (n fastest)
    const int nt = wgid - mg * NT;
    const int b = mg >> 2;                  // MT == 4
    const int l0 = (mg & (MT - 1)) * BM;
    const int n0 = nt * BN;

    const int tid = threadIdx.x;
    const int lane = tid & 63;
    const int wv = tid >> 6;
    const int wr = wv >> 1, wc = wv & 1;    // 2x2 wave grid

    const unsigned short* inb = in + (size_t)b * (LIN + 2) * CI;

    f32x4 acc[4][NW_N];
#pragma unroll
    for (int m = 0; m < 4; ++m)
#pragma unroll
        for (int n = 0; n < NW_N; ++n) acc[m][n] = (f32x4){0.f, 0.f, 0.f, 0.f};

    const int lrow = lane >> 2;             // 0..15
    const int lch = lane & 3;               // 16B chunk

    for (int kb = 0; kb < KC; ++kb) {
        const int kin = kb * BK;
        const unsigned short* abase = inb + (size_t)l0 * CI + kin + lch * 8;
        // A: rows l0 .. l0+143 (padded buffer; overrun stays inside d_ws, rows >129 unused)
        for (int g = wv; g < AGRP; g += 4) {
            GL2LDS(abase + (size_t)(g * 16 + lrow) * CI, As + g * 512);
        }
        // B: 3 tap tiles of BN x 32
        for (int g2 = wv; g2 < BGRP; g2 += 4) {
            const int t = g2 / GPT, gr = g2 - t * GPT;
            const unsigned short* gb =
                wg + (size_t)(n0 + gr * 16 + lrow) * (3 * CI) + (size_t)t * CI + kin + lch * 8;
            GL2LDS(gb, Bs + g2 * 512);
        }
        __syncthreads();
        {
            const int fr = lane & 15, kg = lane >> 4;
#pragma unroll
            for (int t = 0; t < 3; ++t) {
                bf16x8 aF[4], bF[NW_N];
#pragma unroll
                for (int m = 0; m < 4; ++m)
                    aF[m] = *reinterpret_cast<const bf16x8*>(
                        As + (t + wr * 64 + m * 16 + fr) * BK + kg * 8);
#pragma unroll
                for (int n = 0; n < NW_N; ++n)
                    bF[n] = *reinterpret_cast<const bf16x8*>(
                        Bs + ((size_t)t * BN + wc * (BN / 2) + n * 16 + fr) * BK + kg * 8);
#pragma unroll
                for (int m = 0; m < 4; ++m)
#pragma unroll
                    for (int n = 0; n < NW_N; ++n)
                        acc[m][n] = __builtin_amdgcn_mfma_f32_16x16x32_bf16(aF[m], bF[n], acc[m][n], 0, 0, 0);
            }
        }
        __syncthreads();
    }

    // epilogue: bias + ReLU -> bf16; C/D layout col=lane&15, row=(lane>>4)*4+reg
    const int fr = lane & 15, fq = lane >> 4;
    float bv[NW_N];
#pragma unroll
    for (int n = 0; n < NW_N; ++n) bv[n] = bias[n0 + wc * (BN / 2) + n * 16 + fr];
    unsigned short* outb = out + (size_t)b * (LIN + 2) * CO;
#pragma unroll
    for (int m = 0; m < 4; ++m)
#pragma unroll
        for (int qy = 0; qy < 4; ++qy) {
            const int grow = l0 + wr * 64 + m * 16 + fq * 4 + qy + 1;
            unsigned short* orow = outb + (size_t)grow * CO + n0 + wc * (BN / 2) + fr;
#pragma unroll
            for (int n = 0; n < NW_N; ++n) {
                const float v = fmaxf(acc[m][n][qy] + bv[n], 0.f);
                orow[n * 16] = f2bf(v);
            }
        }
}

// ---------------------------------------------------------------- LayerNorm over bf16 padded buffer (in place)

__global__ void ln_kernel(unsigned short* __restrict__ h, const float* __restrict__ g,
                          const float* __restrict__ be) {
    const int row = blockIdx.x, lane = threadIdx.x;
    const int b = row >> 9, l = row & (LIN - 1);
    unsigned short* hr = h + ((size_t)b * (LIN + 2) + l + 1) * DM;
    float v[6];
    float s = 0.f;
#pragma unroll
    for (int j = 0; j < 6; ++j) { v[j] = bf2f(hr[lane + 64 * j]); s += v[j]; }
    s = wred(s);
    const float mean = s * (1.f / DM);
    float vs = 0.f;
#pragma unroll
    for (int j = 0; j < 6; ++j) { const float d = v[j] - mean; vs += d * d; }
    vs = wred(vs);
    const float rstd = rsqrtf(vs * (1.f / DM) + LN_EPS);
#pragma unroll
    for (int j = 0; j < 6; ++j) {
        const int c = lane + 64 * j;
        hr[c] = f2bf((v[j] - mean) * rstd * g[c] + be[c]);
    }
}

// ---------------------------------------------------------------- LayerNorm + linear(384->1), bf16 in, f32 out

__global__ void ln_linear_kernel(const unsigned short* __restrict__ h, const float* __restrict__ g,
                                 const float* __restrict__ be, const float* __restrict__ wl,
                                 const float* __restrict__ bl, float* __restrict__ dur) {
    const int row = blockIdx.x, lane = threadIdx.x;
    const int b = row >> 9, l = row & (LIN - 1);
    const unsigned short* hr = h + ((size_t)b * (LIN + 2) + l + 1) * DM;
    float v[6];
    float s = 0.f;
#pragma unroll
    for (int j = 0; j < 6; ++j) { v[j] = bf2f(hr[lane + 64 * j]); s += v[j]; }
    s = wred(s);
    const float mean = s * (1.f / DM);
    float vs = 0.f;
#pragma unroll
    for (int j = 0; j < 6; ++j) { const float d = v[j] - mean; vs += d * d; }
    vs = wred(vs);
    const float rstd = rsqrtf(vs * (1.f / DM) + LN_EPS);
    float dot = 0.f;
#pragma unroll
    for (int j = 0; j < 6; ++j) {
        const int c = lane + 64 * j;
        dot += ((v[j] - mean) * rstd * g[c] + be[c]) * wl[c];
    }
    dot = wred(dot);
    if (lane == 0) dur[row] = dot + bl[0];
}

// ---------------------------------------------------------------- launch

extern "C" void kernel_launch(void* const* d_in, const int* in_sizes, int n_in,
                              void* d_out, int out_size, void* d_ws, size_t ws_size,
                              hipStream_t stream) {
    const float* x   = (const float*)d_in[0];
    const int*   tgt = (const int*)d_in[1];
    const float* w1  = (const float*)d_in[3];
    const float* b1  = (const float*)d_in[4];
    const float* w2  = (const float*)d_in[5];
    const float* b2  = (const float*)d_in[6];
    const float* g1  = (const float*)d_in[7];
    const float* be1 = (const float*)d_in[8];
    const float* w3  = (const float*)d_in[9];
    const float* b3  = (const float*)d_in[10];
    const float* w4  = (const float*)d_in[11];
    const float* b4  = (const float*)d_in[12];
    const float* g2  = (const float*)d_in[13];
    const float* be2 = (const float*)d_in[14];
    const float* wl  = (const float*)d_in[15];
    const float* bl  = (const float*)d_in[16];

    float* out = (float*)d_out;                         // (16, 4096, 384) f32
    float* dur = out + (size_t)NB * MELMAX * DM;        // (16, 512) f32

    unsigned short* ws = (unsigned short*)d_ws;
    unsigned short* xb   = ws;                                 // (16, 514, 384)  also conv4 out
    unsigned short* hbig = xb + (size_t)NB * (LIN + 2) * DM;   // (16, 514, 1536) conv1/conv3 out
    unsigned short* h2b  = hbig + (size_t)NB * (LIN + 2) * DC; // (16, 514, 384)  conv2 out
    unsigned short* wg1  = h2b + (size_t)NB * (LIN + 2) * DM;  // (1536, 1152)
    unsigned short* wg2  = wg1 + (size_t)DC * 3 * DM;          // (384, 4608)
    unsigned short* wg3  = wg2 + (size_t)DM * 3 * DC;          // (1536, 1152)
    unsigned short* wg4  = wg3 + (size_t)DC * 3 * DM;          // (384, 4608)
    int* cum = (int*)(wg4 + (size_t)DM * 3 * DC);              // (16, 512)

    // ---- output 0: length regulate
    cumsum_kernel<<<NB, LIN, 0, stream>>>(tgt, cum);
    gather_kernel<<<(NB * MELMAX) / 4, 256, 0, stream>>>(x, cum, out);

    // ---- prep
    zpad_kernel<<<NB * 2, 256, 0, stream>>>(xb, DM);
    zpad_kernel<<<NB * 2, 256, 0, stream>>>(hbig, DC);
    zpad_kernel<<<NB * 2, 256, 0, stream>>>(h2b, DM);
    cast_x_kernel<<<(NB * LIN * DM / 4 + 255) / 256, 256, 0, stream>>>(x, xb);
    wcast_kernel<DM, DC><<<(DC * DM + 255) / 256, 256, 0, stream>>>(w1, wg1);
    wcast_kernel<DC, DM><<<(DM * DC + 255) / 256, 256, 0, stream>>>(w2, wg2);
    wcast_kernel<DM, DC><<<(DC * DM + 255) / 256, 256, 0, stream>>>(w3, wg3);
    wcast_kernel<DC, DM><<<(DM * DC + 255) / 256, 256, 0, stream>>>(w4, wg4);

    // ---- output 1: duration predictor (bf16 MFMA convs)
    conv_mfma_kernel<DM, DC, 128><<<NB * (LIN / 128) * (DC / 128), 256, 0, stream>>>(xb, wg1, b1, hbig);
    conv_mfma_kernel<DC, DM, 64><<<NB * (LIN / 128) * (DM / 64), 256, 0, stream>>>(hbig, wg2, b2, h2b);
    ln_kernel<<<NB * LIN, 64, 0, stream>>>(h2b, g1, be1);
    conv_mfma_kernel<DM, DC, 128><<<NB * (LIN / 128) * (DC / 128), 256, 0, stream>>>(h2b, wg3, b3, hbig);
    conv_mfma_kernel<DC, DM, 64><<<NB * (LIN / 128) * (DM / 64), 256, 0, stream>>>(hbig, wg4, b4, xb);
    ln_linear_kernel<<<NB * LIN, 64, 0, stream>>>(xb, g2, be2, wl, bl, dur);
}

// Round 4
// 231.870 us; speedup vs baseline: 8.7515x; 1.0461x over previous
//
#include <hip/hip_runtime.h>
#include <hip/hip_bf16.h>
#include <cstddef>
#include <cstdint>

#define NB 16
#define LIN 512
#define DM 384
#define DC 1536
#define MELMAX 4096
#define LN_EPS 1e-5f

typedef __bf16 bf16x8 __attribute__((ext_vector_type(8)));
typedef float f32x4 __attribute__((ext_vector_type(4)));

#define GL2LDS(gp, lp)                                                                \
    __builtin_amdgcn_global_load_lds((const __attribute__((address_space(1))) void*)(gp), \
                                     (__attribute__((address_space(3))) void*)(lp), 16, 0, 0)

__device__ __forceinline__ float wred(float v) {
#pragma unroll
    for (int m = 32; m >= 1; m >>= 1) v += __shfl_xor(v, m, 64);
    return v;
}

__device__ __forceinline__ unsigned short f2bf(float f) {
    __hip_bfloat16 h = __float2bfloat16(f);
    return *reinterpret_cast<unsigned short*>(&h);
}

__device__ __forceinline__ float bf2f(unsigned short u) {
    return __uint_as_float(((unsigned)u) << 16);
}

// ---------------------------------------------------------------- cumsum (per batch, Hillis-Steele)

__global__ void cumsum_kernel(const int* __restrict__ tgt, int* __restrict__ cum) {
    __shared__ int s[LIN];
    const int b = blockIdx.x, tid = threadIdx.x;
    s[tid] = tgt[b * LIN + tid];
    __syncthreads();
    for (int off = 1; off < LIN; off <<= 1) {
        int v = (tid >= off) ? s[tid - off] : 0;
        __syncthreads();
        s[tid] += v;
        __syncthreads();
    }
    cum[b * LIN + tid] = s[tid];
}

// ---------------------------------------------------------------- length-regulate gather

__global__ __launch_bounds__(256) void gather_kernel(const float* __restrict__ x,
                                                     const int* __restrict__ cum,
                                                     float* __restrict__ out) {
    const int wid = (blockIdx.x * 256 + threadIdx.x) >> 6;
    const int lane = threadIdx.x & 63;
    const int b = wid >> 12;
    const int t = wid & (MELMAX - 1);
    const int* c = cum + b * LIN;
    const int total = c[LIN - 1];
    float4* orow = reinterpret_cast<float4*>(out + ((size_t)b * MELMAX + t) * DM);
    if (t < total) {
        int lo = 0, hi = LIN;
        while (lo < hi) { int mid = (lo + hi) >> 1; if (c[mid] > t) hi = mid; else lo = mid + 1; }
        const int idx = lo < (LIN - 1) ? lo : (LIN - 1);
        const float4* xrow = reinterpret_cast<const float4*>(x + ((size_t)b * LIN + idx) * DM);
#pragma unroll
        for (int j = 0; j < 2; ++j) {
            const int p = lane + 64 * j;
            if (p < DM / 4) orow[p] = xrow[p];
        }
    } else {
        const float4 z = make_float4(0.f, 0.f, 0.f, 0.f);
#pragma unroll
        for (int j = 0; j < 2; ++j) {
            const int p = lane + 64 * j;
            if (p < DM / 4) orow[p] = z;
        }
    }
}

// ---------------------------------------------------------------- small prep kernels (fused launches)

// zero pad rows (row 0, row LIN+1) of the three padded bf16 buffers in one launch
__global__ void zpad3_kernel(unsigned short* __restrict__ xb, unsigned short* __restrict__ hb,
                             unsigned short* __restrict__ h2) {
    const int i = blockIdx.x;               // 0..95
    const int buf = i >> 5, rem = i & 31;
    const int b = rem >> 1, row = (rem & 1) ? (LIN + 1) : 0;
    unsigned short* p = buf == 0 ? xb : (buf == 1 ? hb : h2);
    const int rl = buf == 1 ? DC : DM;
    unsigned short* base = p + ((size_t)b * (LIN + 2) + row) * rl;
    for (int c = threadIdx.x; c < rl; c += 256) base[c] = 0;
}

__global__ void cast_x_kernel(const float* __restrict__ x, unsigned short* __restrict__ xb) {
    const int idx = blockIdx.x * 256 + threadIdx.x;
    const int total = NB * LIN * DM / 4;
    if (idx >= total) return;
    const float4 v = reinterpret_cast<const float4*>(x)[idx];
    const int e = idx * 4;
    const int b = e / (LIN * DM);
    const int rem = e - b * (LIN * DM);
    const int l = rem / DM;
    const int c = rem - l * DM;
    ushort4 o;
    o.x = f2bf(v.x); o.y = f2bf(v.y); o.z = f2bf(v.z); o.w = f2bf(v.w);
    *reinterpret_cast<ushort4*>(xb + ((size_t)b * (LIN + 2) + l + 1) * DM + c) = o;
}

// all 4 weights in one launch: w (CO, CI, 3) f32 -> wg (CO, 3*CI) bf16, k = t*CI + ci
__global__ void wcast_all_kernel(const float* __restrict__ w1, const float* __restrict__ w2,
                                 const float* __restrict__ w3, const float* __restrict__ w4,
                                 unsigned short* __restrict__ o1, unsigned short* __restrict__ o2,
                                 unsigned short* __restrict__ o3, unsigned short* __restrict__ o4) {
    const int idx = blockIdx.x * 256 + threadIdx.x;   // (co,ci) pair; DC*DM == DM*DC for all
    if (idx >= DC * DM) return;
    const int which = blockIdx.y;
    const float* w = which == 0 ? w1 : which == 1 ? w2 : which == 2 ? w3 : w4;
    unsigned short* gg = which == 0 ? o1 : which == 1 ? o2 : which == 2 ? o3 : o4;
    const int CI = (which == 0 || which == 2) ? DM : DC;
    const int co = idx / CI, ci = idx - co * CI;
    const float* p = w + (size_t)idx * 3;
    unsigned short* o = gg + (size_t)co * (3 * CI) + ci;
    o[0 * CI] = f2bf(p[0]);
    o[1 * CI] = f2bf(p[1]);
    o[2 * CI] = f2bf(p[2]);
}

// ---------------------------------------------------------------- conv1d(k=3,SAME) as bf16 MFMA GEMM
// Tap-merged + double-buffered 2-phase pipeline: issue next K-block's global_load_lds
// BEFORE computing the current one; single barrier per K-block (its implicit vmcnt(0)
// drain lands after compute has covered the load latency). XCD-chunked swizzle.

template <int CI, int CO, int BN>
__global__ __launch_bounds__(256, 2) void conv_mfma_kernel(const unsigned short* __restrict__ in,
                                                           const unsigned short* __restrict__ wg,
                                                           const float* __restrict__ bias,
                                                           unsigned short* __restrict__ out) {
    constexpr int BM = 128, BK = 32;
    constexpr int KC = CI / BK;             // K-blocks (12 or 48, even)
    constexpr int AROWS = BM + 16;          // 144 staged rows (need BM+2)
    constexpr int AGRP = AROWS / 16;        // 9
    constexpr int GPT = BN / 16;            // row-groups per B tap tile
    constexpr int BGRP = 3 * GPT;           // 24 (BN=128) / 12 (BN=64)
    constexpr int NW_N = BN / 32;           // n-frags per wave
    constexpr int NT = CO / BN;
    constexpr int MT = LIN / BM;            // 4

    __shared__ __align__(16) unsigned short As[2][AROWS * BK];
    __shared__ __align__(16) unsigned short Bs[2][3 * BN * BK];

    // bijective XCD-chunk swizzle (m204)
    const int orig = blockIdx.x, nwg = gridDim.x;
    const int q = nwg >> 3, r = nwg & 7, xcd = orig & 7, o = orig >> 3;
    const int wgid = (xcd < r ? xcd * (q + 1) : r * (q + 1) + (xcd - r) * q) + o;

    const int mg = wgid / NT;               // m-tile (n fastest)
    const int nt = wgid - mg * NT;
    const int b = mg >> 2;                  // MT == 4
    const int l0 = (mg & (MT - 1)) * BM;
    const int n0 = nt * BN;

    const int tid = threadIdx.x;
    const int lane = tid & 63;
    const int wv = tid >> 6;
    const int wr = wv >> 1, wc = wv & 1;    // 2x2 wave grid

    const unsigned short* inb = in + (size_t)b * (LIN + 2) * CI;

    f32x4 acc[4][NW_N];
#pragma unroll
    for (int m = 0; m < 4; ++m)
#pragma unroll
        for (int n = 0; n < NW_N; ++n) acc[m][n] = (f32x4){0.f, 0.f, 0.f, 0.f};

    const int lrow = lane >> 2;             // 0..15
    const int lch = lane & 3;               // 16B chunk
    const int fr = lane & 15, kg = lane >> 4;

    const unsigned short* aroot = inb + (size_t)l0 * CI + lch * 8;
    const unsigned short* broot = wg + (size_t)n0 * (3 * CI) + lch * 8;

#define STAGE(c, kb)                                                                      \
    do {                                                                                  \
        const unsigned short* abase = aroot + (kb) * BK;                                  \
        for (int g = wv; g < AGRP; g += 4)                                                \
            GL2LDS(abase + (size_t)(g * 16 + lrow) * CI, &As[c][g * 512]);                \
        const unsigned short* bbase = broot + (kb) * BK;                                  \
        for (int g2 = wv; g2 < BGRP; g2 += 4) {                                           \
            const int t = g2 / GPT, gr = g2 - t * GPT;                                    \
            GL2LDS(bbase + (size_t)(gr * 16 + lrow) * (3 * CI) + (size_t)t * CI,          \
                   &Bs[c][g2 * 512]);                                                     \
        }                                                                                 \
    } while (0)

#define COMPUTE(c)                                                                        \
    do {                                                                                  \
        _Pragma("unroll")                                                                 \
        for (int t = 0; t < 3; ++t) {                                                     \
            bf16x8 aF[4], bF[NW_N];                                                       \
            _Pragma("unroll")                                                             \
            for (int m = 0; m < 4; ++m)                                                   \
                aF[m] = *reinterpret_cast<const bf16x8*>(                                 \
                    &As[c][(t + wr * 64 + m * 16 + fr) * BK + kg * 8]);                   \
            _Pragma("unroll")                                                             \
            for (int n = 0; n < NW_N; ++n)                                                \
                bF[n] = *reinterpret_cast<const bf16x8*>(                                 \
                    &Bs[c][(t * BN + wc * (BN / 2) + n * 16 + fr) * BK + kg * 8]);        \
            _Pragma("unroll")                                                             \
            for (int m = 0; m < 4; ++m)                                                   \
                _Pragma("unroll")                                                         \
                for (int n = 0; n < NW_N; ++n)                                            \
                    acc[m][n] =                                                           \
                        __builtin_amdgcn_mfma_f32_16x16x32_bf16(aF[m], bF[n], acc[m][n],  \
                                                                0, 0, 0);                 \
        }                                                                                 \
    } while (0)

    STAGE(0, 0);
    __syncthreads();
#pragma unroll 1
    for (int kb = 0; kb < KC; kb += 2) {
        if (kb + 1 < KC) STAGE(1, kb + 1);
        COMPUTE(0);
        __syncthreads();
        if (kb + 2 < KC) STAGE(0, kb + 2);
        if (kb + 1 < KC) {
            COMPUTE(1);
            __syncthreads();
        }
    }
#undef STAGE
#undef COMPUTE

    // epilogue: bias + ReLU -> bf16; C/D layout col=lane&15, row=(lane>>4)*4+reg
    const int fq = lane >> 4;
    float bv[NW_N];
#pragma unroll
    for (int n = 0; n < NW_N; ++n) bv[n] = bias[n0 + wc * (BN / 2) + n * 16 + fr];
    unsigned short* outb = out + (size_t)b * (LIN + 2) * CO;
#pragma unroll
    for (int m = 0; m < 4; ++m)
#pragma unroll
        for (int qy = 0; qy < 4; ++qy) {
            const int grow = l0 + wr * 64 + m * 16 + fq * 4 + qy + 1;
            unsigned short* orow = outb + (size_t)grow * CO + n0 + wc * (BN / 2) + fr;
#pragma unroll
            for (int n = 0; n < NW_N; ++n) {
                const float v = fmaxf(acc[m][n][qy] + bv[n], 0.f);
                orow[n * 16] = f2bf(v);
            }
        }
}

// ---------------------------------------------------------------- LayerNorm over bf16 padded buffer (in place)

__global__ void ln_kernel(unsigned short* __restrict__ h, const float* __restrict__ g,
                          const float* __restrict__ be) {
    const int row = blockIdx.x, lane = threadIdx.x;
    const int b = row >> 9, l = row & (LIN - 1);
    unsigned short* hr = h + ((size_t)b * (LIN + 2) + l + 1) * DM;
    float v[6];
    float s = 0.f;
#pragma unroll
    for (int j = 0; j < 6; ++j) { v[j] = bf2f(hr[lane + 64 * j]); s += v[j]; }
    s = wred(s);
    const float mean = s * (1.f / DM);
    float vs = 0.f;
#pragma unroll
    for (int j = 0; j < 6; ++j) { const float d = v[j] - mean; vs += d * d; }
    vs = wred(vs);
    const float rstd = rsqrtf(vs * (1.f / DM) + LN_EPS);
#pragma unroll
    for (int j = 0; j < 6; ++j) {
        const int c = lane + 64 * j;
        hr[c] = f2bf((v[j] - mean) * rstd * g[c] + be[c]);
    }
}

// ---------------------------------------------------------------- LayerNorm + linear(384->1), bf16 in, f32 out

__global__ void ln_linear_kernel(const unsigned short* __restrict__ h, const float* __restrict__ g,
                                 const float* __restrict__ be, const float* __restrict__ wl,
                                 const float* __restrict__ bl, float* __restrict__ dur) {
    const int row = blockIdx.x, lane = threadIdx.x;
    const int b = row >> 9, l = row & (LIN - 1);
    const unsigned short* hr = h + ((size_t)b * (LIN + 2) + l + 1) * DM;
    float v[6];
    float s = 0.f;
#pragma unroll
    for (int j = 0; j < 6; ++j) { v[j] = bf2f(hr[lane + 64 * j]); s += v[j]; }
    s = wred(s);
    const float mean = s * (1.f / DM);
    float vs = 0.f;
#pragma unroll
    for (int j = 0; j < 6; ++j) { const float d = v[j] - mean; vs += d * d; }
    vs = wred(vs);
    const float rstd = rsqrtf(vs * (1.f / DM) + LN_EPS);
    float dot = 0.f;
#pragma unroll
    for (int j = 0; j < 6; ++j) {
        const int c = lane + 64 * j;
        dot += ((v[j] - mean) * rstd * g[c] + be[c]) * wl[c];
    }
    dot = wred(dot);
    if (lane == 0) dur[row] = dot + bl[0];
}

// ---------------------------------------------------------------- launch

extern "C" void kernel_launch(void* const* d_in, const int* in_sizes, int n_in,
                              void* d_out, int out_size, void* d_ws, size_t ws_size,
                              hipStream_t stream) {
    const float* x   = (const float*)d_in[0];
    const int*   tgt = (const int*)d_in[1];
    const float* w1  = (const float*)d_in[3];
    const float* b1  = (const float*)d_in[4];
    const float* w2  = (const float*)d_in[5];
    const float* b2  = (const float*)d_in[6];
    const float* g1  = (const float*)d_in[7];
    const float* be1 = (const float*)d_in[8];
    const float* w3  = (const float*)d_in[9];
    const float* b3  = (const float*)d_in[10];
    const float* w4  = (const float*)d_in[11];
    const float* b4  = (const float*)d_in[12];
    const float* g2  = (const float*)d_in[13];
    const float* be2 = (const float*)d_in[14];
    const float* wl  = (const float*)d_in[15];
    const float* bl  = (const float*)d_in[16];

    float* out = (float*)d_out;                         // (16, 4096, 384) f32
    float* dur = out + (size_t)NB * MELMAX * DM;        // (16, 512) f32

    unsigned short* ws = (unsigned short*)d_ws;
    unsigned short* xb   = ws;                                 // (16, 514, 384)  also conv4 out
    unsigned short* hbig = xb + (size_t)NB * (LIN + 2) * DM;   // (16, 514, 1536) conv1/conv3 out
    unsigned short* h2b  = hbig + (size_t)NB * (LIN + 2) * DC; // (16, 514, 384)  conv2 out
    unsigned short* wg1  = h2b + (size_t)NB * (LIN + 2) * DM;  // (1536, 1152)
    unsigned short* wg2  = wg1 + (size_t)DC * 3 * DM;          // (384, 4608)
    unsigned short* wg3  = wg2 + (size_t)DM * 3 * DC;          // (1536, 1152)
    unsigned short* wg4  = wg3 + (size_t)DC * 3 * DM;          // (384, 4608)
    int* cum = (int*)(wg4 + (size_t)DM * 3 * DC);              // (16, 512)

    // ---- output 0: length regulate
    cumsum_kernel<<<NB, LIN, 0, stream>>>(tgt, cum);
    gather_kernel<<<(NB * MELMAX) / 4, 256, 0, stream>>>(x, cum, out);

    // ---- prep (fused launches)
    zpad3_kernel<<<NB * 2 * 3, 256, 0, stream>>>(xb, hbig, h2b);
    cast_x_kernel<<<(NB * LIN * DM / 4 + 255) / 256, 256, 0, stream>>>(x, xb);
    wcast_all_kernel<<<dim3((DC * DM + 255) / 256, 4), 256, 0, stream>>>(w1, w2, w3, w4,
                                                                         wg1, wg2, wg3, wg4);

    // ---- output 1: duration predictor (bf16 MFMA convs, 2-phase pipelined)
    conv_mfma_kernel<DM, DC, 128><<<NB * (LIN / 128) * (DC / 128), 256, 0, stream>>>(xb, wg1, b1, hbig);
    conv_mfma_kernel<DC, DM, 64><<<NB * (LIN / 128) * (DM / 64), 256, 0, stream>>>(hbig, wg2, b2, h2b);
    ln_kernel<<<NB * LIN, 64, 0, stream>>>(h2b, g1, be1);
    conv_mfma_kernel<DM, DC, 128><<<NB * (LIN / 128) * (DC / 128), 256, 0, stream>>>(h2b, wg3, b3, hbig);
    conv_mfma_kernel<DC, DM, 64><<<NB * (LIN / 128) * (DM / 64), 256, 0, stream>>>(hbig, wg4, b4, xb);
    ln_linear_kernel<<<NB * LIN, 64, 0, stream>>>(xb, g2, be2, wl, bl, dur);
}